// Round 17
// baseline (195.030 us; speedup 1.0000x reference)
//
#include <hip/hip_runtime.h>
#include <hip/hip_bf16.h>
#include <math.h>

#define HH 160
#define WW 160
#define HWsz (HH*WW)

typedef short bf16x8 __attribute__((ext_vector_type(8)));
typedef float f32x4  __attribute__((ext_vector_type(4)));
typedef float f32x2  __attribute__((ext_vector_type(2)));

typedef const __attribute__((address_space(1))) void* gptr_t;
typedef __attribute__((address_space(3))) void* lptr_t;

__device__ inline ushort f2bf(float f) {
    unsigned int u = __float_as_uint(f);
    unsigned int r = (u + 0x7FFFu + ((u >> 16) & 1u)) >> 16;
    return (ushort)r;
}

__device__ inline void unpk8(uint4 u, float* f) {
    f[0] = __uint_as_float(u.x << 16); f[1] = __uint_as_float(u.x & 0xFFFF0000u);
    f[2] = __uint_as_float(u.y << 16); f[3] = __uint_as_float(u.y & 0xFFFF0000u);
    f[4] = __uint_as_float(u.z << 16); f[5] = __uint_as_float(u.z & 0xFFFF0000u);
    f[6] = __uint_as_float(u.w << 16); f[7] = __uint_as_float(u.w & 0xFFFF0000u);
}

// packed-f32 helpers (VOP3P; 2 lanes of f32 per issue)
__device__ inline f32x2 unpk2(unsigned u) {
    f32x2 f;
    f[0] = __uint_as_float(u << 16);
    f[1] = __uint_as_float(u & 0xFFFF0000u);
    return f;
}
__device__ inline f32x2 pk_mul(f32x2 a, f32x2 b) {
    f32x2 d;
    asm("v_pk_mul_f32 %0, %1, %2" : "=v"(d) : "v"(a), "v"(b));
    return d;
}
__device__ inline f32x2 pk_fma(f32x2 a, f32x2 b, f32x2 c) {
    f32x2 d;
    asm("v_pk_fma_f32 %0, %1, %2, %3" : "=v"(d) : "v"(a), "v"(b), "v"(c));
    return d;
}

// ---------------------------------------------------------------------------
// ALL weight packing in one launch (unchanged).
// ---------------------------------------------------------------------------
__global__ __launch_bounds__(256)
void pack_all(const float* __restrict__ fw2, const float* __restrict__ fw3,
              const float* __restrict__ ow1, const float* __restrict__ ow2,
              const float* __restrict__ ow3, const float* __restrict__ dw,
              ushort* __restrict__ w2p, ushort* __restrict__ w3p,
              ushort* __restrict__ o1p, ushort* __restrict__ o2p,
              ushort* __restrict__ o3p, ushort* __restrict__ wmp)
{
    const int seg = blockIdx.y;
    const int idx = blockIdx.x * 256 + threadIdx.x;

    if (seg == 5) {   // mdcn weights
        if (idx >= 18 * 4 * 64) return;
        const int lane = idx & 63;
        const int mt   = (idx >> 6) & 3;
        const int chunk = idx >> 8;
        const int o  = mt * 16 + (lane & 15);
        const int gk = chunk * 4 + (lane >> 4);
        const int g  = gk / 9, k = gk % 9;
        ushort v[8];
#pragma unroll
        for (int j = 0; j < 8; ++j)
            v[j] = f2bf(dw[((size_t)o * 64 + g * 8 + j) * 9 + k]);
        uint4 pk;
        pk.x = (unsigned)v[0] | ((unsigned)v[1] << 16);
        pk.y = (unsigned)v[2] | ((unsigned)v[3] << 16);
        pk.z = (unsigned)v[4] | ((unsigned)v[5] << 16);
        pk.w = (unsigned)v[6] | ((unsigned)v[7] << 16);
        *(uint4*)(wmp + (size_t)idx * 8) = pk;
        return;
    }

    const float* w; ushort* wp; int Cout, Cin, MT_TOT, CIC;
    switch (seg) {
        case 0: w = fw2; wp = w2p; Cout = 64;  Cin = 64;  MT_TOT = 4;  CIC = 2; break;
        case 1: w = fw3; wp = w3p; Cout = 64;  Cin = 64;  MT_TOT = 4;  CIC = 2; break;
        case 2: w = ow1; wp = o1p; Cout = 64;  Cin = 128; MT_TOT = 4;  CIC = 4; break;
        case 3: w = ow2; wp = o2p; Cout = 64;  Cin = 64;  MT_TOT = 4;  CIC = 2; break;
        default: w = ow3; wp = o3p; Cout = 216; Cin = 64; MT_TOT = 16; CIC = 2; break;
    }
    const int total = 9 * CIC * MT_TOT * 64;
    if (idx >= total) return;
    const int lane = idx & 63;
    int t = idx >> 6;
    const int mt  = t % MT_TOT; t /= MT_TOT;
    const int cic = t % CIC;    t /= CIC;
    const int tap = t;
    const int co  = mt * 16 + (lane & 15);
    const int ci0 = cic * 32 + (lane >> 4) * 8;
    ushort v[8];
#pragma unroll
    for (int j = 0; j < 8; ++j) {
        const int ci = ci0 + j;
        float f = 0.f;
        if (co < Cout && ci < Cin) f = w[((size_t)co * Cin + ci) * 9 + tap];
        v[j] = f2bf(f);
    }
    uint4 pk;
    pk.x = (unsigned)v[0] | ((unsigned)v[1] << 16);
    pk.y = (unsigned)v[2] | ((unsigned)v[3] << 16);
    pk.z = (unsigned)v[4] | ((unsigned)v[5] << 16);
    pk.w = (unsigned)v[6] | ((unsigned)v[7] << 16);
    *(uint4*)(wp + (size_t)idx * 8) = pk;
}

// ---------------------------------------------------------------------------
// MFMA implicit-GEMM 3x3 conv — round-13/16 structure (194 µs baseline):
// global_load_lds DMA for both staging paths; 80.4 KB LDS -> 2 blocks/CU.
// OMODE: 0 = bf16 NHWC; 1 = +fused ref-copy/ftsg-repack;
//        3 = split raw: offsets uint (outv) + SIGMOIDED masks bf16 (aux).
// ---------------------------------------------------------------------------
template<int CI_STEPS, bool CONCAT, bool RELU, int OMODE>
__global__ __launch_bounds__(256, 2)
void mfma_conv(const ushort* __restrict__ in, const ushort* __restrict__ wp,
               const float* __restrict__ bias, void* __restrict__ outv,
               int Cout, int MT_TOT, int COG,
               float* __restrict__ outmain, ushort* __restrict__ aux)
{
    constexpr int ROWS = 8, HR = ROWS + 2, NT = 4;
    constexpr int C8   = 8;
    constexpr int CICT = 2 * CI_STEPS;
    constexpr int CIN  = CICT * 32;
    __shared__ uint4 s_in4[HR * 34 * C8];    // 43520 B
    __shared__ uint4 s_a4[9 * 4 * 64];       // 36864 B (half-K A-frags)

    const int tid = threadIdx.x;
    const int lane = tid & 63, wid = tid >> 6;
    const int lane15 = lane & 15, lgrp = lane >> 4;
    const int bz = blockIdx.z;
    const int frame = bz / COG, cog = bz % COG;
    const int x0 = blockIdx.x * 32, y0 = blockIdx.y * ROWS;
    const bool interior = (blockIdx.x >= 1) & (blockIdx.x <= 3) &
                          (blockIdx.y >= 1) & (blockIdx.y <= 18);

    const ushort* src = nullptr; const ushort* srcRef = nullptr; const ushort* srcCur = nullptr;
    if (CONCAT) {
        const int fidx = (frame < 2) ? frame : frame + 1;
        srcRef = in + (size_t)2 * HWsz * 64;
        srcCur = in + (size_t)fidx * HWsz * 64;
    } else {
        src = in + (size_t)frame * HWsz * CIN;
    }

    f32x4 acc[4][NT];
#pragma unroll
    for (int m = 0; m < 4; ++m)
#pragma unroll
        for (int n = 0; n < NT; ++n) acc[m][n] = (f32x4){0.f, 0.f, 0.f, 0.f};

    const uint4* wp4 = (const uint4*)wp;
    const int wrow = wid * 2;
    const int mtg0 = cog * 4;

#pragma unroll
    for (int step = 0; step < CI_STEPS; ++step) {
#pragma unroll
        for (int half = 0; half < 2; ++half) {
            // ---- stage input tile (first half of each step only) ----
            if (half == 0) {
                if (interior) {
                    auto issue = [&](int i, int it) {
                        const int slot = i & 7;
                        const int rem  = i >> 3;
                        const int col  = rem % 34, row = rem / 34;
                        const int c8l  = slot ^ (col & 7);
                        const int gy = y0 + row - 1, gx = x0 + col - 1;
                        const ushort* g;
                        if (CONCAT) {
                            const ushort* sp = (step == 0) ? srcRef : srcCur;
                            g = sp + (size_t)(gy * WW + gx) * 64 + c8l * 8;
                        } else {
                            g = src + (size_t)(gy * WW + gx) * CIN + (step * C8 + c8l) * 8;
                        }
                        __builtin_amdgcn_global_load_lds(
                            (gptr_t)g,
                            (lptr_t)((char*)s_in4 + (size_t)(it * 256 + wid * 64) * 16),
                            16, 0, 0);
                    };
#pragma unroll
                    for (int it = 0; it < 10; ++it)
                        issue(it * 256 + tid, it);
                    if (tid < 160) issue(2560 + tid, 10);
                } else {
                    for (int i = tid; i < HR * 34 * C8; i += 256) {
                        const int ci8l = i & (C8 - 1);
                        const int rem = i / C8;
                        const int col = rem % 34, row = rem / 34;
                        const int gy = y0 + row - 1, gx = x0 + col - 1;
                        const int gci8 = step * C8 + ci8l;
                        uint4 v = {0u, 0u, 0u, 0u};
                        if (gy >= 0 && gy < HH && gx >= 0 && gx < WW) {
                            if (CONCAT) {
                                const ushort* sp = (gci8 < 8) ? srcRef : srcCur;
                                v = *(const uint4*)(sp + (size_t)(gy * WW + gx) * 64 + (gci8 & 7) * 8);
                            } else {
                                v = *(const uint4*)(src + (size_t)(gy * WW + gx) * CIN + gci8 * 8);
                            }
                        }
                        s_in4[(row * 34 + col) * C8 + (ci8l ^ (col & 7))] = v;
                    }
                }
            }
            // ---- stage A-fragments for this half-K: pure DMA ----
#pragma unroll
            for (int it = 0; it < 9; ++it) {
                const int kkg = half * 9 + it;
                const int tap = kkg >> 1, cic = kkg & 1;
                const uint4* g = wp4 +
                    ((size_t)(tap * CICT + step * 2 + cic) * MT_TOT + mtg0 + wid) * 64 + lane;
                __builtin_amdgcn_global_load_lds(
                    (gptr_t)g,
                    (lptr_t)((char*)s_a4 + (size_t)(it * 256 + wid * 64) * 16),
                    16, 0, 0);
            }
            __syncthreads();   // drains vmcnt(0): all DMA writes visible

            // ---- pure LDS+MFMA half-K loop ----
#pragma unroll
            for (int kkl = 0; kkl < 9; ++kkl) {
                const int kkg = half * 9 + kkl;
                const int tap = kkg >> 1, cic = kkg & 1;
                const int dy  = tap / 3 - 1;
                const int dxp = tap % 3;
                bf16x8 a[4];
#pragma unroll
                for (int mt = 0; mt < 4; ++mt)
                    a[mt] = *(const bf16x8*)&s_a4[(kkl * 4 + mt) * 64 + lane];
#pragma unroll
                for (int nt = 0; nt < NT; ++nt) {
                    const int row_l = wrow + (nt >> 1) + dy + 1;
                    const int col_l = (nt & 1) * 16 + lane15 + dxp;
                    const bf16x8 b = *(const bf16x8*)
                        &s_in4[(row_l * 34 + col_l) * C8 + ((cic * 4 + lgrp) ^ (col_l & 7))];
#pragma unroll
                    for (int mt = 0; mt < 4; ++mt)
                        acc[mt][nt] = __builtin_amdgcn_mfma_f32_16x16x32_bf16(a[mt], b, acc[mt][nt], 0, 0, 0);
                }
            }
            __syncthreads();
        }
    }

    // ---- epilogue ----
#pragma unroll
    for (int mt = 0; mt < 4; ++mt) {
        const int co = cog * 64 + mt * 16 + lgrp * 4;
        if (co < Cout) {
            const float4 bs = *(const float4*)&bias[co];
#pragma unroll
            for (int nt = 0; nt < NT; ++nt) {
                const int yy = y0 + wrow + (nt >> 1);
                const int xx = x0 + (nt & 1) * 16 + lane15;
                const int hw = yy * WW + xx;
                f32x4 v = acc[mt][nt];
                v[0] += bs.x; v[1] += bs.y; v[2] += bs.z; v[3] += bs.w;
                if (RELU) {
                    v[0] = fmaxf(v[0], 0.f); v[1] = fmaxf(v[1], 0.f);
                    v[2] = fmaxf(v[2], 0.f); v[3] = fmaxf(v[3], 0.f);
                }
                if (OMODE <= 1) {
                    uint2 pk;
                    pk.x = (unsigned)f2bf(v[0]) | ((unsigned)f2bf(v[1]) << 16);
                    pk.y = (unsigned)f2bf(v[2]) | ((unsigned)f2bf(v[3]) << 16);
                    *(uint2*)((ushort*)outv + ((size_t)frame * HWsz + hw) * 64 + co) = pk;
                    if (OMODE == 1) {
                        if (frame == 2) {
#pragma unroll
                            for (int j = 0; j < 4; ++j)
                                outmain[((size_t)(128 + co + j)) * HWsz + hw] = v[j];
                        } else {
                            const int b = (frame < 2) ? frame : frame - 1;
                            *(uint2*)(aux + (((size_t)(b * 8 + (co >> 3)) * HWsz + hw) * 8 + (co & 7))) = pk;
                        }
                    }
                } else {
                    if (co < 144) {
                        const ushort h0 = f2bf(v[0]), h1 = f2bf(v[1]);
                        const ushort h2 = f2bf(v[2]), h3 = f2bf(v[3]);
                        unsigned* roff = (unsigned*)outv + (size_t)frame * 72 * HWsz;
                        roff[(size_t)(co >> 1) * HWsz + hw]       = (unsigned)h0 | ((unsigned)h1 << 16);
                        roff[(size_t)((co >> 1) + 1) * HWsz + hw] = (unsigned)h2 | ((unsigned)h3 << 16);
                    } else {
                        ushort* rmsk = aux + (size_t)frame * 72 * HWsz;
                        const int gk0 = co - 144;
#pragma unroll
                        for (int j = 0; j < 4; ++j) {
                            const float m = 1.f / (1.f + __expf(-v[j]));
                            rmsk[(size_t)(gk0 + j) * HWsz + hw] = f2bf(m);
                        }
                    }
                }
            }
        }
    }
}

// ---------------------------------------------------------------------------
// conv1: Cin=4 NCHW f32 -> 64ch NHWC bf16 (unchanged).
// ---------------------------------------------------------------------------
__global__ __launch_bounds__(256)
void conv1_kernel(const float* __restrict__ x, const float* __restrict__ w,
                  const float* __restrict__ b, ushort* __restrict__ out)
{
    const int fr = blockIdx.z;
    const int t = threadIdx.x;
    const int tx = t & 15, ty = t >> 4;
    const int x0 = blockIdx.x * 16, y0 = blockIdx.y * 16;

    __shared__ float s_x[4][18][18];
    __shared__ float s_w[36][64];
    __shared__ float s_b[64];

    for (int i = t; i < 4 * 18 * 18; i += 256) {
        const int ci = i / 324, rem = i % 324;
        const int yy = rem / 18, xx = rem % 18;
        const int gy = y0 + yy - 1, gx = x0 + xx - 1;
        float v = 0.f;
        if (gy >= 0 && gy < HH && gx >= 0 && gx < WW)
            v = x[((size_t)fr * 4 + ci) * HWsz + gy * WW + gx];
        s_x[ci][yy][xx] = v;
    }
    for (int i = t; i < 36 * 64; i += 256) {
        const int row = i / 64, o = i % 64;
        const int ci = row / 9, tap = row % 9;
        s_w[row][o] = w[((size_t)o * 4 + ci) * 9 + tap];
    }
    if (t < 64) s_b[t] = b[t];
    __syncthreads();

    float acc[64];
#pragma unroll
    for (int i = 0; i < 64; ++i) acc[i] = 0.f;

#pragma unroll
    for (int ci = 0; ci < 4; ++ci) {
#pragma unroll
        for (int tap = 0; tap < 9; ++tap) {
            const float v = s_x[ci][ty + tap / 3][tx + tap % 3];
            const float4* wr = (const float4*)&s_w[ci * 9 + tap][0];
#pragma unroll
            for (int o4 = 0; o4 < 16; ++o4) {
                const float4 wv = wr[o4];
                acc[o4 * 4 + 0] = fmaf(v, wv.x, acc[o4 * 4 + 0]);
                acc[o4 * 4 + 1] = fmaf(v, wv.y, acc[o4 * 4 + 1]);
                acc[o4 * 4 + 2] = fmaf(v, wv.z, acc[o4 * 4 + 2]);
                acc[o4 * 4 + 3] = fmaf(v, wv.w, acc[o4 * 4 + 3]);
            }
        }
    }

    ushort* ob = out + ((size_t)fr * HWsz + (y0 + ty) * WW + (x0 + tx)) * 64;
#pragma unroll
    for (int o8 = 0; o8 < 8; ++o8) {
        ushort v[8];
#pragma unroll
        for (int j = 0; j < 8; ++j)
            v[j] = f2bf(fmaxf(acc[o8 * 8 + j] + s_b[o8 * 8 + j], 0.f));
        uint4 pk;
        pk.x = (unsigned)v[0] | ((unsigned)v[1] << 16);
        pk.y = (unsigned)v[2] | ((unsigned)v[3] << 16);
        pk.z = (unsigned)v[4] | ((unsigned)v[5] << 16);
        pk.w = (unsigned)v[6] | ((unsigned)v[7] << 16);
        *(uint4*)(ob + o8 * 8) = pk;
    }
}

// ---------------------------------------------------------------------------
// MDCN v8: round-16 structure (2-deep gather pipeline, two half-K dw
// stages) with the bilinear combine rewritten in PACKED f32 math
// (v_pk_mul_f32 / v_pk_fma_f32): channel pairs per dword, 2 FMAs/issue.
// Combine drops ~68 -> ~52 VALU ops per chunk and the FMA-pipe time halves.
// ---------------------------------------------------------------------------
__global__ __launch_bounds__(512, 4)
void mdcn_mfma(const ushort* __restrict__ ftsg, const unsigned* __restrict__ roffg,
               const ushort* __restrict__ rmskg,
               const ushort* __restrict__ wmp, const float* __restrict__ db,
               float* __restrict__ out)
{
    __shared__ uint4 s_w4[9 * 4 * 64];   // 36864 B (half of the 18 chunks)

    const int b    = blockIdx.z;
    const int fidx = (b < 2) ? b : b + 1;
    const int tid  = threadIdx.x;
    const int lane = tid & 63, wid = tid >> 6;
    const int lane15 = lane & 15, lgrp = lane >> 4;
    const int x = blockIdx.x * 16 + lane15;
    const int y = blockIdx.y * 8 + wid;
    const int hw = y * WW + x;

    const uint4* wmp4 = (const uint4*)wmp;
    for (int i = tid; i < 9 * 4 * 64; i += 512) s_w4[i] = wmp4[i];

    const unsigned* roff = roffg + (size_t)b * 72 * HWsz;
    const ushort*   rmsk = rmskg + (size_t)b * 72 * HWsz;

    __syncthreads();

    f32x4 acc[4];
#pragma unroll
    for (int m = 0; m < 4; ++m) acc[m] = (f32x4){0.f, 0.f, 0.f, 0.f};

    // prep chunk n: read roff/rmsk, compute 4 bilinear weights, issue gathers
    auto prep = [&](int n, uint4* u, float* w) {
        const int gk = n * 4 + lgrp;
        const int gg = gk / 9, k9 = gk - 9 * gg;
        const int kyy = k9 / 3 - 1, kxx = k9 - (k9 / 3) * 3 - 1;
        const unsigned op = roff[(size_t)gk * HWsz + hw];
        const float oy = __uint_as_float(op << 16);
        const float ox = __uint_as_float(op & 0xFFFF0000u);
        const float mv = __uint_as_float((unsigned)rmsk[(size_t)gk * HWsz + hw] << 16);

        const float py = oy + (float)(y + kyy);
        const float px = ox + (float)(x + kxx);
        const float y0f = floorf(py), x0f = floorf(px);
        const float tyf = py - y0f, txf = px - x0f;
        const int y0 = (int)y0f, x0i = (int)x0f;
        const int y1 = y0 + 1, x1 = x0i + 1;
        const bool vy0 = (y0 >= 0) & (y0 < HH);
        const bool vy1 = (y1 >= 0) & (y1 < HH);
        const bool vx0 = (x0i >= 0) & (x0i < WW);
        const bool vx1 = (x1 >= 0) & (x1 < WW);
        const int yc0 = min(max(y0, 0), HH - 1), yc1 = min(max(y1, 0), HH - 1);
        const int xc0 = min(max(x0i, 0), WW - 1), xc1 = min(max(x1, 0), WW - 1);
        const float a0 = (1.f - tyf) * mv, a1 = tyf * mv;
        w[0] = (vy0 && vx0) ? a0 * (1.f - txf) : 0.f;
        w[1] = (vy0 && vx1) ? a0 * txf         : 0.f;
        w[2] = (vy1 && vx0) ? a1 * (1.f - txf) : 0.f;
        w[3] = (vy1 && vx1) ? a1 * txf         : 0.f;

        const ushort* pb = ftsg + (size_t)(b * 8 + gg) * HWsz * 8;
        u[0] = *(const uint4*)(pb + (size_t)(yc0 * WW + xc0) * 8);
        u[1] = *(const uint4*)(pb + (size_t)(yc0 * WW + xc1) * 8);
        u[2] = *(const uint4*)(pb + (size_t)(yc1 * WW + xc0) * 8);
        u[3] = *(const uint4*)(pb + (size_t)(yc1 * WW + xc1) * 8);
    };

    uint4 Au[4], Bu[4], Cu[4];
    float Aw[4], Bw[4], Cw[4];
    prep(0, Au, Aw);
    prep(1, Bu, Bw);

#pragma unroll
    for (int half = 0; half < 2; ++half) {
        if (half) {
            __syncthreads();   // all waves done computing half 0
            for (int i = tid; i < 9 * 4 * 64; i += 512)
                s_w4[i] = wmp4[9 * 4 * 64 + i];
            __syncthreads();
        }
#pragma unroll
        for (int gl = 0; gl < 9; ++gl) {
            const int g = half * 9 + gl;
            if (g + 2 < 18) prep(g + 2, Cu, Cw);

            // packed-f32 bilinear combine: channel pairs per dword
            const f32x2 W00 = {Aw[0], Aw[0]};
            const f32x2 W01 = {Aw[1], Aw[1]};
            const f32x2 W10 = {Aw[2], Aw[2]};
            const f32x2 W11 = {Aw[3], Aw[3]};
            uint4 bpk;
#define COMB(DW, OUTW)                                                        \
            {                                                                 \
                f32x2 s2 = pk_mul(unpk2(Au[3].DW), W11);                      \
                s2 = pk_fma(unpk2(Au[2].DW), W10, s2);                        \
                s2 = pk_fma(unpk2(Au[1].DW), W01, s2);                        \
                s2 = pk_fma(unpk2(Au[0].DW), W00, s2);                        \
                asm("v_cvt_pk_bf16_f32 %0, %1, %2"                            \
                    : "=v"(bpk.OUTW) : "v"(s2[0]), "v"(s2[1]));               \
            }
            COMB(x, x)
            COMB(y, y)
            COMB(z, z)
            COMB(w, w)
#undef COMB
            const bf16x8 bfrag = __builtin_bit_cast(bf16x8, bpk);

#pragma unroll
            for (int mt = 0; mt < 4; ++mt) {
                const bf16x8 a = *(const bf16x8*)&s_w4[(gl * 4 + mt) * 64 + lane];
                acc[mt] = __builtin_amdgcn_mfma_f32_16x16x32_bf16(a, bfrag, acc[mt], 0, 0, 0);
            }

            // rotate pipeline: A <- B <- C
#pragma unroll
            for (int j = 0; j < 4; ++j) {
                Au[j] = Bu[j]; Aw[j] = Bw[j];
                Bu[j] = Cu[j]; Bw[j] = Cw[j];
            }
        }
    }

    float* ob = out + (size_t)fidx * 64 * HWsz + hw;
#pragma unroll
    for (int mt = 0; mt < 4; ++mt) {
        const int o0 = mt * 16 + lgrp * 4;
        const float4 bs = *(const float4*)&db[o0];
        ob[(size_t)(o0 + 0) * HWsz] = acc[mt][0] + bs.x;
        ob[(size_t)(o0 + 1) * HWsz] = acc[mt][1] + bs.y;
        ob[(size_t)(o0 + 2) * HWsz] = acc[mt][2] + bs.z;
        ob[(size_t)(o0 + 3) * HWsz] = acc[mt][3] + bs.w;
    }
}

extern "C" void kernel_launch(void* const* d_in, const int* in_sizes, int n_in,
                              void* d_out, int out_size, void* d_ws, size_t ws_size,
                              hipStream_t stream)
{
    const float* x   = (const float*)d_in[0];
    const float* fw1 = (const float*)d_in[1];
    const float* fb1 = (const float*)d_in[2];
    const float* fw2 = (const float*)d_in[3];
    const float* fb2 = (const float*)d_in[4];
    const float* fw3 = (const float*)d_in[5];
    const float* fb3 = (const float*)d_in[6];
    const float* ow1 = (const float*)d_in[7];
    const float* ob1 = (const float*)d_in[8];
    const float* ow2 = (const float*)d_in[9];
    const float* ob2 = (const float*)d_in[10];
    const float* ow3 = (const float*)d_in[11];
    const float* ob3 = (const float*)d_in[12];
    const float* dw  = (const float*)d_in[13];
    const float* db  = (const float*)d_in[14];
    float* out = (float*)d_out;

    // ---- workspace layout (ushort units) ----
    ushort* buf1 = (ushort*)d_ws;                     // 5*HW*64
    ushort* buf2 = buf1 + (size_t)5 * HWsz * 64;
    ushort* fts  = buf2 + (size_t)5 * HWsz * 64;
    ushort* ftsg = fts + (size_t)5 * HWsz * 64;       // 4*8*HW*8
    unsigned* roff = (unsigned*)(ftsg + (size_t)4 * 8 * HWsz * 8);  // 4*72*HW uint
    ushort* rmsk = (ushort*)(roff + (size_t)4 * 72 * HWsz);         // 4*72*HW ushort
    ushort* w2p  = rmsk + (size_t)4 * 72 * HWsz;
    ushort* w3p  = w2p + 36864;
    ushort* o1p  = w3p + 36864;
    ushort* o2p  = o1p + 73728;
    ushort* o3p  = o2p + 36864;
    ushort* wmp  = o3p + 147456;

    const dim3 blk(256);

    // ---- weight packing ----
    pack_all<<<dim3(72, 6), blk, 0, stream>>>(fw2, fw3, ow1, ow2, ow3, dw,
                                              w2p, w3p, o1p, o2p, o3p, wmp);

    // ---- feature extraction ----
    conv1_kernel<<<dim3(10, 10, 5), blk, 0, stream>>>(x, fw1, fb1, buf1);
    mfma_conv<1, false, true, 0><<<dim3(5, 20, 5), blk, 0, stream>>>(
        buf1, w2p, fb2, buf2, 64, 4, 1, nullptr, nullptr);
    // conv3: writes fts NHWC + out frame 2 (f32 CHW) + ftsg group-major
    mfma_conv<1, false, true, 1><<<dim3(5, 20, 5), blk, 0, stream>>>(
        buf2, w3p, fb3, fts, 64, 4, 1, out, ftsg);

    // ---- offset network ----
    mfma_conv<2, true, true, 0><<<dim3(5, 20, 4), blk, 0, stream>>>(
        fts, o1p, ob1, buf1, 64, 4, 1, nullptr, nullptr);
    mfma_conv<1, false, true, 0><<<dim3(5, 20, 4), blk, 0, stream>>>(
        buf1, o2p, ob2, buf2, 64, 4, 1, nullptr, nullptr);
    // ow3: split raw writes (offsets uint + sigmoided masks bf16)
    mfma_conv<1, false, false, 3><<<dim3(5, 20, 16), blk, 0, stream>>>(
        buf2, o3p, ob3, roff, 216, 16, 4, nullptr, rmsk);

    // ---- modulated deformable conv + assembly ----
    mdcn_mfma<<<dim3(10, 20, 4), dim3(512), 0, stream>>>(ftsg, roff, rmsk, wmp, db, out);
}

// Round 18
// 194.001 us; speedup vs baseline: 1.0053x; 1.0053x over previous
//
#include <hip/hip_runtime.h>
#include <hip/hip_bf16.h>
#include <math.h>

#define HH 160
#define WW 160
#define HWsz (HH*WW)

typedef short bf16x8 __attribute__((ext_vector_type(8)));
typedef float f32x4  __attribute__((ext_vector_type(4)));

typedef const __attribute__((address_space(1))) void* gptr_t;
typedef __attribute__((address_space(3))) void* lptr_t;

__device__ inline ushort f2bf(float f) {
    unsigned int u = __float_as_uint(f);
    unsigned int r = (u + 0x7FFFu + ((u >> 16) & 1u)) >> 16;
    return (ushort)r;
}

__device__ inline void unpk8(uint4 u, float* f) {
    f[0] = __uint_as_float(u.x << 16); f[1] = __uint_as_float(u.x & 0xFFFF0000u);
    f[2] = __uint_as_float(u.y << 16); f[3] = __uint_as_float(u.y & 0xFFFF0000u);
    f[4] = __uint_as_float(u.z << 16); f[5] = __uint_as_float(u.z & 0xFFFF0000u);
    f[6] = __uint_as_float(u.w << 16); f[7] = __uint_as_float(u.w & 0xFFFF0000u);
}

// ---------------------------------------------------------------------------
// ALL weight packing in one launch.
// ---------------------------------------------------------------------------
__global__ __launch_bounds__(256)
void pack_all(const float* __restrict__ fw2, const float* __restrict__ fw3,
              const float* __restrict__ ow1, const float* __restrict__ ow2,
              const float* __restrict__ ow3, const float* __restrict__ dw,
              ushort* __restrict__ w2p, ushort* __restrict__ w3p,
              ushort* __restrict__ o1p, ushort* __restrict__ o2p,
              ushort* __restrict__ o3p, ushort* __restrict__ wmp)
{
    const int seg = blockIdx.y;
    const int idx = blockIdx.x * 256 + threadIdx.x;

    if (seg == 5) {   // mdcn weights
        if (idx >= 18 * 4 * 64) return;
        const int lane = idx & 63;
        const int mt   = (idx >> 6) & 3;
        const int chunk = idx >> 8;
        const int o  = mt * 16 + (lane & 15);
        const int gk = chunk * 4 + (lane >> 4);
        const int g  = gk / 9, k = gk % 9;
        ushort v[8];
#pragma unroll
        for (int j = 0; j < 8; ++j)
            v[j] = f2bf(dw[((size_t)o * 64 + g * 8 + j) * 9 + k]);
        uint4 pk;
        pk.x = (unsigned)v[0] | ((unsigned)v[1] << 16);
        pk.y = (unsigned)v[2] | ((unsigned)v[3] << 16);
        pk.z = (unsigned)v[4] | ((unsigned)v[5] << 16);
        pk.w = (unsigned)v[6] | ((unsigned)v[7] << 16);
        *(uint4*)(wmp + (size_t)idx * 8) = pk;
        return;
    }

    const float* w; ushort* wp; int Cout, Cin, MT_TOT, CIC;
    switch (seg) {
        case 0: w = fw2; wp = w2p; Cout = 64;  Cin = 64;  MT_TOT = 4;  CIC = 2; break;
        case 1: w = fw3; wp = w3p; Cout = 64;  Cin = 64;  MT_TOT = 4;  CIC = 2; break;
        case 2: w = ow1; wp = o1p; Cout = 64;  Cin = 128; MT_TOT = 4;  CIC = 4; break;
        case 3: w = ow2; wp = o2p; Cout = 64;  Cin = 64;  MT_TOT = 4;  CIC = 2; break;
        default: w = ow3; wp = o3p; Cout = 216; Cin = 64; MT_TOT = 16; CIC = 2; break;
    }
    const int total = 9 * CIC * MT_TOT * 64;
    if (idx >= total) return;
    const int lane = idx & 63;
    int t = idx >> 6;
    const int mt  = t % MT_TOT; t /= MT_TOT;
    const int cic = t % CIC;    t /= CIC;
    const int tap = t;
    const int co  = mt * 16 + (lane & 15);
    const int ci0 = cic * 32 + (lane >> 4) * 8;
    ushort v[8];
#pragma unroll
    for (int j = 0; j < 8; ++j) {
        const int ci = ci0 + j;
        float f = 0.f;
        if (co < Cout && ci < Cin) f = w[((size_t)co * Cin + ci) * 9 + tap];
        v[j] = f2bf(f);
    }
    uint4 pk;
    pk.x = (unsigned)v[0] | ((unsigned)v[1] << 16);
    pk.y = (unsigned)v[2] | ((unsigned)v[3] << 16);
    pk.z = (unsigned)v[4] | ((unsigned)v[5] << 16);
    pk.w = (unsigned)v[6] | ((unsigned)v[7] << 16);
    *(uint4*)(wp + (size_t)idx * 8) = pk;
}

// ---------------------------------------------------------------------------
// MFMA implicit-GEMM 3x3 conv — round-13/16 structure (194 µs baseline):
// global_load_lds DMA for both staging paths; 80.4 KB LDS -> 2 blocks/CU.
// At its LDS-traffic roofline: 64 KB LDS/chunk-round per CU ~ 753 cyc vs
// 155 cyc MFMA -> 21% MfmaUtil ceiling (measured 22%).
// OMODE: 0 = bf16 NHWC; 1 = +fused ref-copy/ftsg-repack;
//        3 = split raw: offsets uint (outv) + SIGMOIDED masks bf16 (aux).
// ---------------------------------------------------------------------------
template<int CI_STEPS, bool CONCAT, bool RELU, int OMODE>
__global__ __launch_bounds__(256, 2)
void mfma_conv(const ushort* __restrict__ in, const ushort* __restrict__ wp,
               const float* __restrict__ bias, void* __restrict__ outv,
               int Cout, int MT_TOT, int COG,
               float* __restrict__ outmain, ushort* __restrict__ aux)
{
    constexpr int ROWS = 8, HR = ROWS + 2, NT = 4;
    constexpr int C8   = 8;
    constexpr int CICT = 2 * CI_STEPS;
    constexpr int CIN  = CICT * 32;
    __shared__ uint4 s_in4[HR * 34 * C8];    // 43520 B
    __shared__ uint4 s_a4[9 * 4 * 64];       // 36864 B (half-K A-frags)

    const int tid = threadIdx.x;
    const int lane = tid & 63, wid = tid >> 6;
    const int lane15 = lane & 15, lgrp = lane >> 4;
    const int bz = blockIdx.z;
    const int frame = bz / COG, cog = bz % COG;
    const int x0 = blockIdx.x * 32, y0 = blockIdx.y * ROWS;
    const bool interior = (blockIdx.x >= 1) & (blockIdx.x <= 3) &
                          (blockIdx.y >= 1) & (blockIdx.y <= 18);

    const ushort* src = nullptr; const ushort* srcRef = nullptr; const ushort* srcCur = nullptr;
    if (CONCAT) {
        const int fidx = (frame < 2) ? frame : frame + 1;
        srcRef = in + (size_t)2 * HWsz * 64;
        srcCur = in + (size_t)fidx * HWsz * 64;
    } else {
        src = in + (size_t)frame * HWsz * CIN;
    }

    f32x4 acc[4][NT];
#pragma unroll
    for (int m = 0; m < 4; ++m)
#pragma unroll
        for (int n = 0; n < NT; ++n) acc[m][n] = (f32x4){0.f, 0.f, 0.f, 0.f};

    const uint4* wp4 = (const uint4*)wp;
    const int wrow = wid * 2;
    const int mtg0 = cog * 4;

#pragma unroll
    for (int step = 0; step < CI_STEPS; ++step) {
#pragma unroll
        for (int half = 0; half < 2; ++half) {
            // ---- stage input tile (first half of each step only) ----
            if (half == 0) {
                if (interior) {
                    auto issue = [&](int i, int it) {
                        const int slot = i & 7;
                        const int rem  = i >> 3;
                        const int col  = rem % 34, row = rem / 34;
                        const int c8l  = slot ^ (col & 7);
                        const int gy = y0 + row - 1, gx = x0 + col - 1;
                        const ushort* g;
                        if (CONCAT) {
                            const ushort* sp = (step == 0) ? srcRef : srcCur;
                            g = sp + (size_t)(gy * WW + gx) * 64 + c8l * 8;
                        } else {
                            g = src + (size_t)(gy * WW + gx) * CIN + (step * C8 + c8l) * 8;
                        }
                        __builtin_amdgcn_global_load_lds(
                            (gptr_t)g,
                            (lptr_t)((char*)s_in4 + (size_t)(it * 256 + wid * 64) * 16),
                            16, 0, 0);
                    };
#pragma unroll
                    for (int it = 0; it < 10; ++it)
                        issue(it * 256 + tid, it);
                    if (tid < 160) issue(2560 + tid, 10);
                } else {
                    for (int i = tid; i < HR * 34 * C8; i += 256) {
                        const int ci8l = i & (C8 - 1);
                        const int rem = i / C8;
                        const int col = rem % 34, row = rem / 34;
                        const int gy = y0 + row - 1, gx = x0 + col - 1;
                        const int gci8 = step * C8 + ci8l;
                        uint4 v = {0u, 0u, 0u, 0u};
                        if (gy >= 0 && gy < HH && gx >= 0 && gx < WW) {
                            if (CONCAT) {
                                const ushort* sp = (gci8 < 8) ? srcRef : srcCur;
                                v = *(const uint4*)(sp + (size_t)(gy * WW + gx) * 64 + (gci8 & 7) * 8);
                            } else {
                                v = *(const uint4*)(src + (size_t)(gy * WW + gx) * CIN + gci8 * 8);
                            }
                        }
                        s_in4[(row * 34 + col) * C8 + (ci8l ^ (col & 7))] = v;
                    }
                }
            }
            // ---- stage A-fragments for this half-K: pure DMA ----
#pragma unroll
            for (int it = 0; it < 9; ++it) {
                const int kkg = half * 9 + it;
                const int tap = kkg >> 1, cic = kkg & 1;
                const uint4* g = wp4 +
                    ((size_t)(tap * CICT + step * 2 + cic) * MT_TOT + mtg0 + wid) * 64 + lane;
                __builtin_amdgcn_global_load_lds(
                    (gptr_t)g,
                    (lptr_t)((char*)s_a4 + (size_t)(it * 256 + wid * 64) * 16),
                    16, 0, 0);
            }
            __syncthreads();   // drains vmcnt(0): all DMA writes visible

            // ---- pure LDS+MFMA half-K loop ----
#pragma unroll
            for (int kkl = 0; kkl < 9; ++kkl) {
                const int kkg = half * 9 + kkl;
                const int tap = kkg >> 1, cic = kkg & 1;
                const int dy  = tap / 3 - 1;
                const int dxp = tap % 3;
                bf16x8 a[4];
#pragma unroll
                for (int mt = 0; mt < 4; ++mt)
                    a[mt] = *(const bf16x8*)&s_a4[(kkl * 4 + mt) * 64 + lane];
#pragma unroll
                for (int nt = 0; nt < NT; ++nt) {
                    const int row_l = wrow + (nt >> 1) + dy + 1;
                    const int col_l = (nt & 1) * 16 + lane15 + dxp;
                    const bf16x8 b = *(const bf16x8*)
                        &s_in4[(row_l * 34 + col_l) * C8 + ((cic * 4 + lgrp) ^ (col_l & 7))];
#pragma unroll
                    for (int mt = 0; mt < 4; ++mt)
                        acc[mt][nt] = __builtin_amdgcn_mfma_f32_16x16x32_bf16(a[mt], b, acc[mt][nt], 0, 0, 0);
                }
            }
            __syncthreads();
        }
    }

    // ---- epilogue ----
#pragma unroll
    for (int mt = 0; mt < 4; ++mt) {
        const int co = cog * 64 + mt * 16 + lgrp * 4;
        if (co < Cout) {
            const float4 bs = *(const float4*)&bias[co];
#pragma unroll
            for (int nt = 0; nt < NT; ++nt) {
                const int yy = y0 + wrow + (nt >> 1);
                const int xx = x0 + (nt & 1) * 16 + lane15;
                const int hw = yy * WW + xx;
                f32x4 v = acc[mt][nt];
                v[0] += bs.x; v[1] += bs.y; v[2] += bs.z; v[3] += bs.w;
                if (RELU) {
                    v[0] = fmaxf(v[0], 0.f); v[1] = fmaxf(v[1], 0.f);
                    v[2] = fmaxf(v[2], 0.f); v[3] = fmaxf(v[3], 0.f);
                }
                if (OMODE <= 1) {
                    uint2 pk;
                    pk.x = (unsigned)f2bf(v[0]) | ((unsigned)f2bf(v[1]) << 16);
                    pk.y = (unsigned)f2bf(v[2]) | ((unsigned)f2bf(v[3]) << 16);
                    *(uint2*)((ushort*)outv + ((size_t)frame * HWsz + hw) * 64 + co) = pk;
                    if (OMODE == 1) {
                        if (frame == 2) {
#pragma unroll
                            for (int j = 0; j < 4; ++j)
                                outmain[((size_t)(128 + co + j)) * HWsz + hw] = v[j];
                        } else {
                            const int b = (frame < 2) ? frame : frame - 1;
                            *(uint2*)(aux + (((size_t)(b * 8 + (co >> 3)) * HWsz + hw) * 8 + (co & 7))) = pk;
                        }
                    }
                } else {
                    if (co < 144) {
                        const ushort h0 = f2bf(v[0]), h1 = f2bf(v[1]);
                        const ushort h2 = f2bf(v[2]), h3 = f2bf(v[3]);
                        unsigned* roff = (unsigned*)outv + (size_t)frame * 72 * HWsz;
                        roff[(size_t)(co >> 1) * HWsz + hw]       = (unsigned)h0 | ((unsigned)h1 << 16);
                        roff[(size_t)((co >> 1) + 1) * HWsz + hw] = (unsigned)h2 | ((unsigned)h3 << 16);
                    } else {
                        ushort* rmsk = aux + (size_t)frame * 72 * HWsz;
                        const int gk0 = co - 144;
#pragma unroll
                        for (int j = 0; j < 4; ++j) {
                            const float m = 1.f / (1.f + __expf(-v[j]));
                            rmsk[(size_t)(gk0 + j) * HWsz + hw] = f2bf(m);
                        }
                    }
                }
            }
        }
    }
}

// ---------------------------------------------------------------------------
// conv1: Cin=4 NCHW f32 -> 64ch NHWC bf16.
// ---------------------------------------------------------------------------
__global__ __launch_bounds__(256)
void conv1_kernel(const float* __restrict__ x, const float* __restrict__ w,
                  const float* __restrict__ b, ushort* __restrict__ out)
{
    const int fr = blockIdx.z;
    const int t = threadIdx.x;
    const int tx = t & 15, ty = t >> 4;
    const int x0 = blockIdx.x * 16, y0 = blockIdx.y * 16;

    __shared__ float s_x[4][18][18];
    __shared__ float s_w[36][64];
    __shared__ float s_b[64];

    for (int i = t; i < 4 * 18 * 18; i += 256) {
        const int ci = i / 324, rem = i % 324;
        const int yy = rem / 18, xx = rem % 18;
        const int gy = y0 + yy - 1, gx = x0 + xx - 1;
        float v = 0.f;
        if (gy >= 0 && gy < HH && gx >= 0 && gx < WW)
            v = x[((size_t)fr * 4 + ci) * HWsz + gy * WW + gx];
        s_x[ci][yy][xx] = v;
    }
    for (int i = t; i < 36 * 64; i += 256) {
        const int row = i / 64, o = i % 64;
        const int ci = row / 9, tap = row % 9;
        s_w[row][o] = w[((size_t)o * 4 + ci) * 9 + tap];
    }
    if (t < 64) s_b[t] = b[t];
    __syncthreads();

    float acc[64];
#pragma unroll
    for (int i = 0; i < 64; ++i) acc[i] = 0.f;

#pragma unroll
    for (int ci = 0; ci < 4; ++ci) {
#pragma unroll
        for (int tap = 0; tap < 9; ++tap) {
            const float v = s_x[ci][ty + tap / 3][tx + tap % 3];
            const float4* wr = (const float4*)&s_w[ci * 9 + tap][0];
#pragma unroll
            for (int o4 = 0; o4 < 16; ++o4) {
                const float4 wv = wr[o4];
                acc[o4 * 4 + 0] = fmaf(v, wv.x, acc[o4 * 4 + 0]);
                acc[o4 * 4 + 1] = fmaf(v, wv.y, acc[o4 * 4 + 1]);
                acc[o4 * 4 + 2] = fmaf(v, wv.z, acc[o4 * 4 + 2]);
                acc[o4 * 4 + 3] = fmaf(v, wv.w, acc[o4 * 4 + 3]);
            }
        }
    }

    ushort* ob = out + ((size_t)fr * HWsz + (y0 + ty) * WW + (x0 + tx)) * 64;
#pragma unroll
    for (int o8 = 0; o8 < 8; ++o8) {
        ushort v[8];
#pragma unroll
        for (int j = 0; j < 8; ++j)
            v[j] = f2bf(fmaxf(acc[o8 * 8 + j] + s_b[o8 * 8 + j], 0.f));
        uint4 pk;
        pk.x = (unsigned)v[0] | ((unsigned)v[1] << 16);
        pk.y = (unsigned)v[2] | ((unsigned)v[3] << 16);
        pk.z = (unsigned)v[4] | ((unsigned)v[5] << 16);
        pk.w = (unsigned)v[6] | ((unsigned)v[7] << 16);
        *(uint4*)(ob + o8 * 8) = pk;
    }
}

// ---------------------------------------------------------------------------
// MDCN v7 (round-16 best: 44.6 µs): 2-deep gather pipeline, two half-K dw
// stages, scalar-fma combine (round-17 packed-f32 variant regressed:
// VALUBusy fell but duration rose -> latency-bound, reverted).
// ---------------------------------------------------------------------------
__global__ __launch_bounds__(512, 4)
void mdcn_mfma(const ushort* __restrict__ ftsg, const unsigned* __restrict__ roffg,
               const ushort* __restrict__ rmskg,
               const ushort* __restrict__ wmp, const float* __restrict__ db,
               float* __restrict__ out)
{
    __shared__ uint4 s_w4[9 * 4 * 64];   // 36864 B (half of the 18 chunks)

    const int b    = blockIdx.z;
    const int fidx = (b < 2) ? b : b + 1;
    const int tid  = threadIdx.x;
    const int lane = tid & 63, wid = tid >> 6;
    const int lane15 = lane & 15, lgrp = lane >> 4;
    const int x = blockIdx.x * 16 + lane15;
    const int y = blockIdx.y * 8 + wid;
    const int hw = y * WW + x;

    const uint4* wmp4 = (const uint4*)wmp;
    for (int i = tid; i < 9 * 4 * 64; i += 512) s_w4[i] = wmp4[i];

    const unsigned* roff = roffg + (size_t)b * 72 * HWsz;
    const ushort*   rmsk = rmskg + (size_t)b * 72 * HWsz;

    __syncthreads();

    f32x4 acc[4];
#pragma unroll
    for (int m = 0; m < 4; ++m) acc[m] = (f32x4){0.f, 0.f, 0.f, 0.f};

    // prep chunk n: read roff/rmsk, compute 4 bilinear weights, issue gathers
    auto prep = [&](int n, uint4* u, float* w) {
        const int gk = n * 4 + lgrp;
        const int gg = gk / 9, k9 = gk - 9 * gg;
        const int kyy = k9 / 3 - 1, kxx = k9 - (k9 / 3) * 3 - 1;
        const unsigned op = roff[(size_t)gk * HWsz + hw];
        const float oy = __uint_as_float(op << 16);
        const float ox = __uint_as_float(op & 0xFFFF0000u);
        const float mv = __uint_as_float((unsigned)rmsk[(size_t)gk * HWsz + hw] << 16);

        const float py = oy + (float)(y + kyy);
        const float px = ox + (float)(x + kxx);
        const float y0f = floorf(py), x0f = floorf(px);
        const float tyf = py - y0f, txf = px - x0f;
        const int y0 = (int)y0f, x0i = (int)x0f;
        const int y1 = y0 + 1, x1 = x0i + 1;
        const bool vy0 = (y0 >= 0) & (y0 < HH);
        const bool vy1 = (y1 >= 0) & (y1 < HH);
        const bool vx0 = (x0i >= 0) & (x0i < WW);
        const bool vx1 = (x1 >= 0) & (x1 < WW);
        const int yc0 = min(max(y0, 0), HH - 1), yc1 = min(max(y1, 0), HH - 1);
        const int xc0 = min(max(x0i, 0), WW - 1), xc1 = min(max(x1, 0), WW - 1);
        const float a0 = (1.f - tyf) * mv, a1 = tyf * mv;
        w[0] = (vy0 && vx0) ? a0 * (1.f - txf) : 0.f;
        w[1] = (vy0 && vx1) ? a0 * txf         : 0.f;
        w[2] = (vy1 && vx0) ? a1 * (1.f - txf) : 0.f;
        w[3] = (vy1 && vx1) ? a1 * txf         : 0.f;

        const ushort* pb = ftsg + (size_t)(b * 8 + gg) * HWsz * 8;
        u[0] = *(const uint4*)(pb + (size_t)(yc0 * WW + xc0) * 8);
        u[1] = *(const uint4*)(pb + (size_t)(yc0 * WW + xc1) * 8);
        u[2] = *(const uint4*)(pb + (size_t)(yc1 * WW + xc0) * 8);
        u[3] = *(const uint4*)(pb + (size_t)(yc1 * WW + xc1) * 8);
    };

    uint4 Au[4], Bu[4], Cu[4];
    float Aw[4], Bw[4], Cw[4];
    prep(0, Au, Aw);
    prep(1, Bu, Bw);

#pragma unroll
    for (int half = 0; half < 2; ++half) {
        if (half) {
            __syncthreads();   // all waves done computing half 0
            for (int i = tid; i < 9 * 4 * 64; i += 512)
                s_w4[i] = wmp4[9 * 4 * 64 + i];
            __syncthreads();
        }
#pragma unroll
        for (int gl = 0; gl < 9; ++gl) {
            const int g = half * 9 + gl;
            if (g + 2 < 18) prep(g + 2, Cu, Cw);

            float f0[8], f1[8], f2[8], f3[8];
            unpk8(Au[0], f0); unpk8(Au[1], f1); unpk8(Au[2], f2); unpk8(Au[3], f3);
            float s[8];
#pragma unroll
            for (int c = 0; c < 8; ++c)
                s[c] = fmaf(Aw[3], f3[c], fmaf(Aw[2], f2[c],
                        fmaf(Aw[1], f1[c], Aw[0] * f0[c])));
            uint4 bpk;
            asm("v_cvt_pk_bf16_f32 %0, %1, %2" : "=v"(bpk.x) : "v"(s[0]), "v"(s[1]));
            asm("v_cvt_pk_bf16_f32 %0, %1, %2" : "=v"(bpk.y) : "v"(s[2]), "v"(s[3]));
            asm("v_cvt_pk_bf16_f32 %0, %1, %2" : "=v"(bpk.z) : "v"(s[4]), "v"(s[5]));
            asm("v_cvt_pk_bf16_f32 %0, %1, %2" : "=v"(bpk.w) : "v"(s[6]), "v"(s[7]));
            const bf16x8 bfrag = __builtin_bit_cast(bf16x8, bpk);

#pragma unroll
            for (int mt = 0; mt < 4; ++mt) {
                const bf16x8 a = *(const bf16x8*)&s_w4[(gl * 4 + mt) * 64 + lane];
                acc[mt] = __builtin_amdgcn_mfma_f32_16x16x32_bf16(a, bfrag, acc[mt], 0, 0, 0);
            }

            // rotate pipeline: A <- B <- C
#pragma unroll
            for (int j = 0; j < 4; ++j) {
                Au[j] = Bu[j]; Aw[j] = Bw[j];
                Bu[j] = Cu[j]; Bw[j] = Cw[j];
            }
        }
    }

    float* ob = out + (size_t)fidx * 64 * HWsz + hw;
#pragma unroll
    for (int mt = 0; mt < 4; ++mt) {
        const int o0 = mt * 16 + lgrp * 4;
        const float4 bs = *(const float4*)&db[o0];
        ob[(size_t)(o0 + 0) * HWsz] = acc[mt][0] + bs.x;
        ob[(size_t)(o0 + 1) * HWsz] = acc[mt][1] + bs.y;
        ob[(size_t)(o0 + 2) * HWsz] = acc[mt][2] + bs.z;
        ob[(size_t)(o0 + 3) * HWsz] = acc[mt][3] + bs.w;
    }
}

extern "C" void kernel_launch(void* const* d_in, const int* in_sizes, int n_in,
                              void* d_out, int out_size, void* d_ws, size_t ws_size,
                              hipStream_t stream)
{
    const float* x   = (const float*)d_in[0];
    const float* fw1 = (const float*)d_in[1];
    const float* fb1 = (const float*)d_in[2];
    const float* fw2 = (const float*)d_in[3];
    const float* fb2 = (const float*)d_in[4];
    const float* fw3 = (const float*)d_in[5];
    const float* fb3 = (const float*)d_in[6];
    const float* ow1 = (const float*)d_in[7];
    const float* ob1 = (const float*)d_in[8];
    const float* ow2 = (const float*)d_in[9];
    const float* ob2 = (const float*)d_in[10];
    const float* ow3 = (const float*)d_in[11];
    const float* ob3 = (const float*)d_in[12];
    const float* dw  = (const float*)d_in[13];
    const float* db  = (const float*)d_in[14];
    float* out = (float*)d_out;

    // ---- workspace layout (ushort units) ----
    ushort* buf1 = (ushort*)d_ws;                     // 5*HW*64
    ushort* buf2 = buf1 + (size_t)5 * HWsz * 64;
    ushort* fts  = buf2 + (size_t)5 * HWsz * 64;
    ushort* ftsg = fts + (size_t)5 * HWsz * 64;       // 4*8*HW*8
    unsigned* roff = (unsigned*)(ftsg + (size_t)4 * 8 * HWsz * 8);  // 4*72*HW uint
    ushort* rmsk = (ushort*)(roff + (size_t)4 * 72 * HWsz);         // 4*72*HW ushort
    ushort* w2p  = rmsk + (size_t)4 * 72 * HWsz;
    ushort* w3p  = w2p + 36864;
    ushort* o1p  = w3p + 36864;
    ushort* o2p  = o1p + 73728;
    ushort* o3p  = o2p + 36864;
    ushort* wmp  = o3p + 147456;

    const dim3 blk(256);

    // ---- weight packing ----
    pack_all<<<dim3(72, 6), blk, 0, stream>>>(fw2, fw3, ow1, ow2, ow3, dw,
                                              w2p, w3p, o1p, o2p, o3p, wmp);

    // ---- feature extraction ----
    conv1_kernel<<<dim3(10, 10, 5), blk, 0, stream>>>(x, fw1, fb1, buf1);
    mfma_conv<1, false, true, 0><<<dim3(5, 20, 5), blk, 0, stream>>>(
        buf1, w2p, fb2, buf2, 64, 4, 1, nullptr, nullptr);
    // conv3: writes fts NHWC + out frame 2 (f32 CHW) + ftsg group-major
    mfma_conv<1, false, true, 1><<<dim3(5, 20, 5), blk, 0, stream>>>(
        buf2, w3p, fb3, fts, 64, 4, 1, out, ftsg);

    // ---- offset network ----
    mfma_conv<2, true, true, 0><<<dim3(5, 20, 4), blk, 0, stream>>>(
        fts, o1p, ob1, buf1, 64, 4, 1, nullptr, nullptr);
    mfma_conv<1, false, true, 0><<<dim3(5, 20, 4), blk, 0, stream>>>(
        buf1, o2p, ob2, buf2, 64, 4, 1, nullptr, nullptr);
    // ow3: split raw writes (offsets uint + sigmoided masks bf16)
    mfma_conv<1, false, false, 3><<<dim3(5, 20, 16), blk, 0, stream>>>(
        buf2, o3p, ob3, roff, 216, 16, 4, nullptr, rmsk);

    // ---- modulated deformable conv + assembly ----
    mdcn_mfma<<<dim3(10, 20, 4), dim3(512), 0, stream>>>(ftsg, roff, rmsk, wmp, db, out);
}